// Round 11
// baseline (147.490 us; speedup 1.0000x reference)
//
#include <hip/hip_runtime.h>
#include <hip/hip_bf16.h>
#include <math.h>

#define B_ 4
#define S_ 512
#define H_ 768
#define NH_ 12
#define E_ 24
#define TE_ 20
#define TD_ 20
#define R_ 97
#define DIN_ 1576   // 2*H + TE + TD
#define KPAD_ 1600  // DIN padded to multiple of 32
#define KS_MLP 50   // KPAD/32
#define MF_MLP 140  // 2240/16 m-frags
#define KS_HTI 16   // 512/32
#define P_ 552      // E*(E-1)
#define L_ 2208     // B*P
#define NB_ 12      // H/64
#define NF_ 7       // n-frags of 16 cols covering 97 -> 112

typedef __bf16 bf16x8 __attribute__((ext_vector_type(8)));
typedef float f32x4 __attribute__((ext_vector_type(4)));

__device__ __forceinline__ unsigned short f2bf(float f) {
  union { float f; unsigned u; } c; c.f = f;
  unsigned r = c.u + 0x7FFF + ((c.u >> 16) & 1);
  return (unsigned short)(r >> 16);
}
__device__ __forceinline__ float bf2f(unsigned short b) {
  union { unsigned u; float f; } c; c.u = ((unsigned)b) << 16;
  return c.f;
}
__device__ __forceinline__ unsigned pk2(float a, float b) {
  return (unsigned)f2bf(a) | ((unsigned)f2bf(b) << 16);
}
// async global->LDS, 16B per lane; LDS dest = wave-uniform base + lane*16
__device__ __forceinline__ void gload_lds16(const uint4* g, uint4* l) {
  __builtin_amdgcn_global_load_lds(
      (const __attribute__((address_space(1))) unsigned*)(const void*)g,
      (__attribute__((address_space(3))) unsigned*)(void*)l, 16, 0, 0);
}

// ---------------------------------------------------------------------------
// K1: per-entity gathered attention-row sum over heads + entity features.
// ---------------------------------------------------------------------------
__global__ void ent_prep(const float* __restrict__ attn, const float* __restrict__ hs,
                         const int* __restrict__ head, const int* __restrict__ tail,
                         float* __restrict__ ent_att, float* __restrict__ ent_feat) {
  int be = blockIdx.x;
  int b = be / E_;
  int hd = head[be], tl = tail[be];
  int tid = threadIdx.x;
  const float* abase = attn + (size_t)b * NH_ * S_ * S_;
  for (int s = tid; s < S_; s += 256) {
    float acc = 0.f;
#pragma unroll
    for (int nh = 0; nh < NH_; ++nh) {
      const float* ap = abase + (size_t)nh * S_ * S_;
      acc += ap[(size_t)hd * S_ + s] + ap[(size_t)tl * S_ + s];
    }
    ent_att[(size_t)be * S_ + s] = 0.5f * acc;
  }
  const float* hb = hs + (size_t)b * S_ * H_;
  for (int k = tid; k < H_; k += 256) {
    ent_feat[(size_t)be * H_ + k] = 0.5f * (hb[(size_t)hd * H_ + k] + hb[(size_t)tl * H_ + k]);
  }
}

// ---------------------------------------------------------------------------
// K2: pairwise attention product + mask + normalize; pair metadata.
// ---------------------------------------------------------------------------
__global__ void pair_att(const float* __restrict__ ent_att, const float* __restrict__ mask,
                         const int* __restrict__ head, const int* __restrict__ tail,
                         const int* __restrict__ etype,
                         float* __restrict__ ht_att, int* __restrict__ meta) {
  int l = blockIdx.x;
  int b = l / P_, p = l % P_;
  int i0 = p / (E_ - 1), rem = p % (E_ - 1);
  int i1 = rem + (rem >= i0 ? 1 : 0);
  int tid = threadIdx.x;
  if (tid == 0) {
    meta[0 * L_ + l] = b * E_ + i0;
    meta[1 * L_ + l] = b * E_ + i1;
    meta[2 * L_ + l] = etype[b * E_ + i0];
    meta[3 * L_ + l] = etype[b * E_ + i1];
    int d = abs(tail[b * E_ + i0] - head[b * E_ + i1]);
    int bk = (d >= 2) + (d >= 4) + (d >= 8) + (d >= 16) + (d >= 32) +
             (d >= 64) + (d >= 128) + (d >= 256) + (d >= 512);
    meta[4 * L_ + l] = bk;
  }
  const float* a0 = ent_att + (size_t)(b * E_ + i0) * S_;
  const float* a1 = ent_att + (size_t)(b * E_ + i1) * S_;
  const float* m = mask + (size_t)b * S_;
  float v0 = a0[tid] * a1[tid] * m[tid];
  float v1 = a0[tid + 256] * a1[tid + 256] * m[tid + 256];
  float loc = v0 + v1;
  for (int o = 32; o > 0; o >>= 1) loc += __shfl_down(loc, o, 64);
  __shared__ float red[4];
  if ((tid & 63) == 0) red[tid >> 6] = loc;
  __syncthreads();
  float tot = red[0] + red[1] + red[2] + red[3];
  float inv = 1.f / (tot + 1e-20f);
  ht_att[(size_t)l * S_ + tid] = v0 * inv;
  ht_att[(size_t)l * S_ + tid + 256] = v1 * inv;
}

// ---------------------------------------------------------------------------
// pack_hs: hs (B,S,H f32) -> bf16 fragment-major [b][ks][nt16(48)][lane][8]
// ---------------------------------------------------------------------------
__global__ void pack_hs(const float* __restrict__ hs, uint4* __restrict__ hsP) {
  int u = blockIdx.x * 256 + threadIdx.x;
  if (u >= B_ * KS_HTI * 48 * 64) return;
  int lane = u & 63;
  int t = u >> 6;
  int nt16 = t % 48;
  int t2 = t / 48;
  int ks = t2 % KS_HTI;
  int b = t2 / KS_HTI;
  int n = nt16 * 16 + (lane & 15);
  int k0 = ks * 32 + ((lane >> 4) << 3);
  const float* src = hs + (size_t)b * S_ * H_;
  unsigned w[4];
#pragma unroll
  for (int q = 0; q < 4; ++q) {
    int k = k0 + 2 * q;
    w[q] = pk2(src[(size_t)k * H_ + n], src[(size_t)(k + 1) * H_ + n]);
  }
  uint4 o; o.x = w[0]; o.y = w[1]; o.z = w[2]; o.w = w[3];
  hsP[u] = o;
}

// ---------------------------------------------------------------------------
// pack_Wmlp: Wh/Wt (DIN,H f32) -> bf16 fragment-major [ks][nt16(48)][lane][8]
// ---------------------------------------------------------------------------
__global__ void pack_Wmlp(const float* __restrict__ Wh, const float* __restrict__ Wt,
                          uint4* __restrict__ WpH, uint4* __restrict__ WpT) {
  int u = blockIdx.x * 256 + threadIdx.x;
  if (u >= KS_MLP * 48 * 64) return;
  const float* W = blockIdx.y ? Wt : Wh;
  uint4* Wp = blockIdx.y ? WpT : WpH;
  int lane = u & 63;
  int t = u >> 6;
  int nt16 = t % 48;
  int ks = t / 48;
  int n = nt16 * 16 + (lane & 15);
  int k0 = ks * 32 + ((lane >> 4) << 3);
  unsigned w[4];
#pragma unroll
  for (int q = 0; q < 4; ++q) {
    int k = k0 + 2 * q;
    float v0 = (k < DIN_) ? W[(size_t)k * H_ + n] : 0.f;
    float v1 = (k + 1 < DIN_) ? W[(size_t)(k + 1) * H_ + n] : 0.f;
    w[q] = pk2(v0, v1);
  }
  uint4 o; o.x = w[0]; o.y = w[1]; o.z = w[2]; o.w = w[3];
  Wp[u] = o;
}

// ---------------------------------------------------------------------------
// pack_allx: gathered A matrices (all_h / all_t) in bf16 frag-major
// [mf(140)][ks(50)][lane][8].
// ---------------------------------------------------------------------------
__global__ void pack_allx(const float* __restrict__ ent_feat, const float* __restrict__ ht_info,
                          const float* __restrict__ ttab, const float* __restrict__ dtab,
                          const int* __restrict__ meta,
                          uint4* __restrict__ axH, uint4* __restrict__ axT) {
  int idx = blockIdx.x * 256 + threadIdx.x;   // 2*7000*64 = 896000 exact
  int lane = idx & 63;
  int unit = idx >> 6;
  int half = unit / (MF_MLP * KS_MLP);
  int rem = unit % (MF_MLP * KS_MLP);
  int mf = rem / KS_MLP, ks = rem % KS_MLP;
  int row = mf * 16 + (lane & 15);
  int k = ks * 32 + ((lane >> 4) << 3);
  uint4 d; d.x = d.y = d.z = d.w = 0;
  if (row < L_) {
    int frow = meta[half * L_ + row];
    int trow = meta[(2 + half) * L_ + row];
    int db = meta[4 * L_ + row];
    if (k < 768) {
      const float* p = ent_feat + (size_t)frow * H_ + k;
      float4 v0 = *(const float4*)p, v1 = *(const float4*)(p + 4);
      d.x = pk2(v0.x, v0.y); d.y = pk2(v0.z, v0.w);
      d.z = pk2(v1.x, v1.y); d.w = pk2(v1.z, v1.w);
    } else if (k < 1536) {
      const float* p = ht_info + (size_t)row * H_ + (k - 768);
      float4 v0 = *(const float4*)p, v1 = *(const float4*)(p + 4);
      d.x = pk2(v0.x, v0.y); d.y = pk2(v0.z, v0.w);
      d.z = pk2(v1.x, v1.y); d.w = pk2(v1.z, v1.w);
    } else {
      float v[8];
#pragma unroll
      for (int j = 0; j < 8; ++j) {
        int e = k + j;
        v[j] = (e < 1556) ? ttab[trow * TE_ + (e - 1536)]
             : (e < 1576) ? dtab[db * TD_ + (e - 1556)] : 0.f;
      }
      d.x = pk2(v[0], v[1]); d.y = pk2(v[2], v[3]);
      d.z = pk2(v[4], v[5]); d.w = pk2(v[6], v[7]);
    }
  }
  (half ? axT : axH)[(size_t)rem * 64 + lane] = d;
}

// ---------------------------------------------------------------------------
// htinfo_mfma v3: BM=64 BN=64 BK=64, 8 K-steps, 4 waves (2m x 2n).
// ---------------------------------------------------------------------------
__global__ __launch_bounds__(256) void htinfo_mfma(
    const float* __restrict__ htatt, const uint4* __restrict__ hsP,
    float* __restrict__ htinfo) {
  int b = blockIdx.z;
  int m0 = blockIdx.x * 64;
  int nt0 = blockIdx.y * 4;
  int tid = threadIdx.x;
  int wave = tid >> 6, lane = tid & 63;
  int wm = wave & 1, wn = wave >> 1;
  __shared__ __align__(16) uint4 Ash[2][512];
  __shared__ __align__(16) uint4 Bsh[2][512];

  f32x4 acc[2][2];
#pragma unroll
  for (int i = 0; i < 2; ++i)
#pragma unroll
    for (int j = 0; j < 2; ++j) acc[i][j] = (f32x4){0.f, 0.f, 0.f, 0.f};

  auto stageB = [&](int s, int buf) {
#pragma unroll
    for (int i = 0; i < 2; ++i) {
      int c = wave * 2 + i;
      int ntl = c >> 1, kslot = c & 1;
      gload_lds16(hsP + ((size_t)(b * KS_HTI + s * 2 + kslot) * 48 + nt0 + ntl) * 64 + lane,
                  &Bsh[buf][c * 64]);
    }
  };
  auto gatherA = [&](int s, int c, uint4& d) {
    int mfl = c >> 1, kslot = c & 1;
    int row = m0 + mfl * 16 + (lane & 15);
    if (row >= P_) { d.x = d.y = d.z = d.w = 0; return; }
    int k = s * 64 + kslot * 32 + ((lane >> 4) << 3);
    const float* p = htatt + ((size_t)b * P_ + row) * S_ + k;
    float4 v0 = *(const float4*)p, v1 = *(const float4*)(p + 4);
    d.x = pk2(v0.x, v0.y); d.y = pk2(v0.z, v0.w);
    d.z = pk2(v1.x, v1.y); d.w = pk2(v1.z, v1.w);
  };

  {
    uint4 a0_, a1_;
    gatherA(0, wave, a0_); gatherA(0, wave + 4, a1_);
    Ash[0][wave * 64 + lane] = a0_;
    Ash[0][(wave + 4) * 64 + lane] = a1_;
    stageB(0, 0);
  }
  __syncthreads();

  for (int s = 0; s < 8; ++s) {
    int cur = s & 1, nxt = cur ^ 1;
    bool more = (s + 1 < 8);
    uint4 aN0, aN1;
    if (more) {
      stageB(s + 1, nxt);
      gatherA(s + 1, wave, aN0); gatherA(s + 1, wave + 4, aN1);
    }
    bf16x8 af[2][2], bf[2][2];
#pragma unroll
    for (int mf = 0; mf < 2; ++mf)
#pragma unroll
      for (int kc = 0; kc < 2; ++kc)
        af[mf][kc] = *(const bf16x8*)&Ash[cur][((wm * 2 + mf) * 2 + kc) * 64 + lane];
#pragma unroll
    for (int nf = 0; nf < 2; ++nf)
#pragma unroll
      for (int kc = 0; kc < 2; ++kc)
        bf[nf][kc] = *(const bf16x8*)&Bsh[cur][((wn * 2 + nf) * 2 + kc) * 64 + lane];
#pragma unroll
    for (int kc = 0; kc < 2; ++kc)
#pragma unroll
      for (int nf = 0; nf < 2; ++nf)
#pragma unroll
        for (int mf = 0; mf < 2; ++mf)
          acc[mf][nf] = __builtin_amdgcn_mfma_f32_16x16x32_bf16(af[mf][kc], bf[nf][kc], acc[mf][nf], 0, 0, 0);
    if (more) {
      Ash[nxt][wave * 64 + lane] = aN0;
      Ash[nxt][(wave + 4) * 64 + lane] = aN1;
    }
    __syncthreads();
  }

#pragma unroll
  for (int mf = 0; mf < 2; ++mf)
#pragma unroll
    for (int nf = 0; nf < 2; ++nf) {
      int n = nt0 * 16 + (wn * 2 + nf) * 16 + (lane & 15);
#pragma unroll
      for (int reg = 0; reg < 4; ++reg) {
        int l = m0 + (wm * 2 + mf) * 16 + ((lane >> 4) << 2) + reg;
        if (l < P_)
          htinfo[((size_t)b * P_ + l) * H_ + n] = acc[mf][nf][reg];
      }
    }
}

// ---------------------------------------------------------------------------
// mlp_mfma v4: pure GEMM with T4 counted-vmcnt depth-3 pipeline.
// Raw s_barrier; vmcnt(4) (one step's 4 loads/wave allowed in flight).
// ---------------------------------------------------------------------------
__global__ __launch_bounds__(256) void mlp_mfma(
    const uint4* __restrict__ Apk_h, const uint4* __restrict__ Apk_t,
    const uint4* __restrict__ Wp_h, const uint4* __restrict__ Wp_t,
    const float* __restrict__ bh, const float* __restrict__ bt,
    float* __restrict__ h1, float* __restrict__ t1) {
  int half = blockIdx.z;
  const uint4* Apk = half ? Apk_t : Apk_h;
  const uint4* Wp = half ? Wp_t : Wp_h;
  const float* bias = half ? bt : bh;
  float* out = half ? t1 : h1;
  int mf0 = blockIdx.x * 4;
  int nt0 = blockIdx.y * 4;
  int tid = threadIdx.x;
  int wave = tid >> 6, lane = tid & 63;
  int wm = wave & 1, wn = wave >> 1;
  __shared__ __align__(16) uint4 Ash[3][512];
  __shared__ __align__(16) uint4 Bsh[3][512];

  f32x4 acc[2][2];
#pragma unroll
  for (int i = 0; i < 2; ++i)
#pragma unroll
    for (int j = 0; j < 2; ++j) acc[i][j] = (f32x4){0.f, 0.f, 0.f, 0.f};

  auto stage = [&](int s, int buf) {
#pragma unroll
    for (int i = 0; i < 2; ++i) {
      int c = wave * 2 + i;
      int cl = c >> 1, kslot = c & 1;
      gload_lds16(Apk + ((size_t)(mf0 + cl) * KS_MLP + s * 2 + kslot) * 64 + lane,
                  &Ash[buf][c * 64]);
      gload_lds16(Wp + ((size_t)(s * 2 + kslot) * 48 + nt0 + cl) * 64 + lane,
                  &Bsh[buf][c * 64]);
    }
  };

  stage(0, 0);
  stage(1, 1);
  __syncthreads();   // drains prologue; bufs 0,1 + nothing else outstanding

  for (int s = 0; s < 25; ++s) {
    // T4: counted wait — the buffer consumed this step was staged 2 steps
    // ago; only the previous step's 4 loads may remain in flight.
    asm volatile("s_waitcnt vmcnt(4)" ::: "memory");
    __builtin_amdgcn_s_barrier();
    if (s + 2 < 25) stage(s + 2, (s + 2) % 3);
    int cur = s % 3;
    bf16x8 af[2][2], bf[2][2];
#pragma unroll
    for (int mf = 0; mf < 2; ++mf)
#pragma unroll
      for (int kc = 0; kc < 2; ++kc)
        af[mf][kc] = *(const bf16x8*)&Ash[cur][((wm * 2 + mf) * 2 + kc) * 64 + lane];
#pragma unroll
    for (int nf = 0; nf < 2; ++nf)
#pragma unroll
      for (int kc = 0; kc < 2; ++kc)
        bf[nf][kc] = *(const bf16x8*)&Bsh[cur][((wn * 2 + nf) * 2 + kc) * 64 + lane];
#pragma unroll
    for (int kc = 0; kc < 2; ++kc)
#pragma unroll
      for (int nf = 0; nf < 2; ++nf)
#pragma unroll
        for (int mf = 0; mf < 2; ++mf)
          acc[mf][nf] = __builtin_amdgcn_mfma_f32_16x16x32_bf16(af[mf][kc], bf[nf][kc], acc[mf][nf], 0, 0, 0);
  }

#pragma unroll
  for (int mf = 0; mf < 2; ++mf)
#pragma unroll
    for (int nf = 0; nf < 2; ++nf) {
      int n = nt0 * 16 + (wn * 2 + nf) * 16 + (lane & 15);
      float bv = bias[n];
#pragma unroll
      for (int reg = 0; reg < 4; ++reg) {
        int l = (mf0 + wm * 2 + mf) * 16 + ((lane >> 4) << 2) + reg;
        if (l < L_)
          out[(size_t)l * H_ + n] = tanhf(acc[mf][nf][reg] + bv);
      }
    }
}

// ---------------------------------------------------------------------------
// K5a: pre-pack clsW -> fragment-major bf16 for the bilinear B-operand.
// ---------------------------------------------------------------------------
__global__ void pack_w(const float* __restrict__ clsW, uint4* __restrict__ Wfrag) {
  int nb = blockIdx.x;            // n*64 + b
  __shared__ float Wls[64][98];
  int tid = threadIdx.x;
  const float* src = clsW + (size_t)nb * 64 * R_;
  for (int idx = tid; idx < 64 * R_; idx += 256) {
    Wls[idx / R_][idx % R_] = src[idx];
  }
  __syncthreads();
  for (int u = tid; u < 896; u += 256) {
    int nf = u >> 7;
    int kc = (u >> 6) & 1;
    int lane = u & 63;
    int r = (lane & 15) + 16 * nf;
    unsigned w[4];
#pragma unroll
    for (int q = 0; q < 4; ++q) {
      int c0 = ((lane >> 4) << 3) + 2 * q + 32 * kc;
      float v0 = (r < R_) ? Wls[c0][r] : 0.f;
      float v1 = (r < R_) ? Wls[c0 + 1][r] : 0.f;
      w[q] = (unsigned)f2bf(v0) | ((unsigned)f2bf(v1) << 16);
    }
    uint4 o; o.x = w[0]; o.y = w[1]; o.z = w[2]; o.w = w[3];
    Wfrag[(size_t)nb * 896 + u] = o;
  }
}

// ---------------------------------------------------------------------------
// K5b v7: bilinear MFMA = R10 shape (2 waves x 64 rows, XCD decode, z-split)
// + T4 counted-vmcnt depth-3 pipeline. Raw s_barrier; vmcnt(7) (one step's
// 7 loads/wave in flight). LDS: Wl[3][896] 43008 + x1s 8320 = 51328 B
// -> 3 blocks/CU.
// ---------------------------------------------------------------------------
__global__ __launch_bounds__(128, 2) void bilinear_mfma(
    const float* __restrict__ h1, const float* __restrict__ t1,
    const uint4* __restrict__ Wfrag, float* __restrict__ part,
    float* __restrict__ part2) {
  int blk = blockIdx.x;
  int xcd = blk & 7;
  int slot = blk >> 3;        // 0..53
  int pg = slot / 18;         // 0..2
  int j = slot % 18;          // l-tile index
  int p = pg * 8 + xcd;       // 0..23
  int n = p >> 1, z = p & 1;
  int l0 = j * 128;
  int tid = threadIdx.x;
  int wave = tid >> 6, lane = tid & 63;
  __shared__ __align__(16) uint4 Wl[3][896];      // depth-3, 43008 B
  __shared__ unsigned short x1s[32][130];         // [b_local][row], padded

  // x1 tile (32 b's for this z, 128 rows) -> LDS transposed, bf16.
  for (int i = tid; i < 1024; i += 128) {
    int l = i >> 3, bq = (i & 7) * 4;
    float4 v = make_float4(0, 0, 0, 0);
    if (l0 + l < L_)
      v = *(const float4*)(h1 + (size_t)(l0 + l) * H_ + n * 64 + z * 32 + bq);
    x1s[bq + 0][l] = f2bf(v.x);
    x1s[bq + 1][l] = f2bf(v.y);
    x1s[bq + 2][l] = f2bf(v.z);
    x1s[bq + 3][l] = f2bf(v.w);
  }

  // x2 fragments (b-invariant): 4 m-frags x 2 kc x 8 f32
  float x2f[4][2][8];
#pragma unroll
  for (int mf = 0; mf < 4; ++mf) {
    int row = l0 + wave * 64 + mf * 16 + (lane & 15);
#pragma unroll
    for (int kc = 0; kc < 2; ++kc) {
      float4 v0 = make_float4(0, 0, 0, 0), v1 = v0;
      if (row < L_) {
        const float* ptr = t1 + (size_t)row * H_ + n * 64 + kc * 32 + ((lane >> 4) << 3);
        v0 = *(const float4*)ptr;
        v1 = *(const float4*)(ptr + 4);
      }
      x2f[mf][kc][0] = v0.x; x2f[mf][kc][1] = v0.y;
      x2f[mf][kc][2] = v0.z; x2f[mf][kc][3] = v0.w;
      x2f[mf][kc][4] = v1.x; x2f[mf][kc][5] = v1.y;
      x2f[mf][kc][6] = v1.z; x2f[mf][kc][7] = v1.w;
    }
  }

  f32x4 acc[4][NF_];
#pragma unroll
  for (int mf = 0; mf < 4; ++mf)
#pragma unroll
    for (int nf = 0; nf < NF_; ++nf)
      acc[mf][nf] = (f32x4){0.f, 0.f, 0.f, 0.f};

  const uint4* gbase = Wfrag + (size_t)n * 64 * 896;
  // stage one b's 896 units: 7 chunks per wave (2 waves cover 14)
  auto stage = [&](int b, int buf) {
    const uint4* gs = gbase + (size_t)b * 896 + (wave * 7) * 64 + lane;
#pragma unroll
    for (int r = 0; r < 7; ++r)
      gload_lds16(gs + r * 64, &Wl[buf][(wave * 7 + r) * 64]);
  };

  stage(z * 32 + 0, 0);
  stage(z * 32 + 1, 1);
  __syncthreads();   // drains prologue (x1s + bufs 0,1); vmcnt now 0

  for (int s = 0; s < 32; ++s) {
    // T4: buffer consumed this step was staged >=2 steps ago; only the
    // previous step's 7 wave-private loads may remain outstanding.
    asm volatile("s_waitcnt vmcnt(7)" ::: "memory");
    __builtin_amdgcn_s_barrier();
    // overwrite target buf[(s+2)%3] was last read at step s-1; the barrier
    // above guarantees both waves finished those reads.
    if (s + 2 < 32) stage(z * 32 + s + 2, (s + 2) % 3);
    int cur = s % 3;
    // compose A-fragments (4 m-frags) for this b
    bf16x8 afr[4][2];
#pragma unroll
    for (int mf = 0; mf < 4; ++mf) {
      float x1v = bf2f(x1s[s][wave * 64 + mf * 16 + (lane & 15)]);
#pragma unroll
      for (int kc = 0; kc < 2; ++kc)
#pragma unroll
        for (int jj = 0; jj < 8; ++jj)
          afr[mf][kc][jj] = (__bf16)(x1v * x2f[mf][kc][jj]);
    }
    // 14 W-frag reads feed 56 MFMAs
#pragma unroll
    for (int nf = 0; nf < NF_; ++nf) {
#pragma unroll
      for (int kc = 0; kc < 2; ++kc) {
        bf16x8 bfr = *(const bf16x8*)&Wl[cur][(nf * 2 + kc) * 64 + lane];
#pragma unroll
        for (int mf = 0; mf < 4; ++mf)
          acc[mf][nf] = __builtin_amdgcn_mfma_f32_16x16x32_bf16(
              afr[mf][kc], bfr, acc[mf][nf], 0, 0, 0);
      }
    }
  }

  float* dst = (z == 0) ? part : part2;
#pragma unroll
  for (int mf = 0; mf < 4; ++mf) {
#pragma unroll
    for (int nf = 0; nf < NF_; ++nf) {
      int r = nf * 16 + (lane & 15);
      if (r < R_) {
#pragma unroll
        for (int reg = 0; reg < 4; ++reg) {
          int l = l0 + wave * 64 + mf * 16 + ((lane >> 4) << 2) + reg;
          if (l < L_)
            dst[((size_t)n * L_ + l) * R_ + r] = acc[mf][nf][reg];
        }
      }
    }
  }
}

// ---------------------------------------------------------------------------
// K6: reduce 24 partial slices (12 in part, 12 in part2), add clsb.
// ---------------------------------------------------------------------------
__global__ void reduce_logits(const float* __restrict__ part, const float* __restrict__ part2,
                              const float* __restrict__ clsb, float* __restrict__ out) {
  int idx = blockIdx.x * 256 + threadIdx.x;
  if (idx < L_ * R_) {
    int r = idx % R_;
    float s = clsb[r];
#pragma unroll
    for (int nn = 0; nn < NB_; ++nn)
      s += part[(size_t)nn * L_ * R_ + idx] + part2[(size_t)nn * L_ * R_ + idx];
    out[idx] = s;
  }
}

extern "C" void kernel_launch(void* const* d_in, const int* in_sizes, int n_in,
                              void* d_out, int out_size, void* d_ws, size_t ws_size,
                              hipStream_t stream) {
  const float* hs   = (const float*)d_in[0];
  const float* attn = (const float*)d_in[1];
  const float* mask = (const float*)d_in[2];
  const int*   head = (const int*)d_in[3];
  const int*   tail = (const int*)d_in[4];
  const int*   etyp = (const int*)d_in[5];
  const float* ttab = (const float*)d_in[6];
  const float* dtab = (const float*)d_in[7];
  const float* Wh   = (const float*)d_in[8];
  const float* bh   = (const float*)d_in[9];
  const float* Wt   = (const float*)d_in[10];
  const float* bt   = (const float*)d_in[11];
  const float* clsW = (const float*)d_in[12];
  const float* clsb = (const float*)d_in[13];
  float* out = (float*)d_out;

  float* ws = (float*)d_ws;
  float* ent_att  = ws; ws += (size_t)B_ * E_ * S_;
  float* ent_feat = ws; ws += (size_t)B_ * E_ * H_;
  float* ht_att   = ws; ws += (size_t)L_ * S_;
  float* ht_info  = ws; ws += (size_t)L_ * H_;
  float* h1       = ws; ws += (size_t)L_ * H_;
  float* t1       = ws; ws += (size_t)L_ * H_;
  float* part     = ws; ws += (size_t)NB_ * L_ * R_;
  uint4* Wpack_h  = (uint4*)ws; ws += (size_t)KS_MLP * 48 * 64 * 4;
  uint4* Wpack_t  = (uint4*)ws; ws += (size_t)KS_MLP * 48 * 64 * 4;
  uint4* hsPack   = (uint4*)ws; ws += (size_t)B_ * KS_HTI * 48 * 64 * 4;
  uint4* Wfrag    = (uint4*)ws; ws += (size_t)NB_ * 64 * 896 * 4;
  uint4* allx_h   = (uint4*)ws; ws += (size_t)MF_MLP * KS_MLP * 64 * 4;
  uint4* allx_t   = (uint4*)ws; ws += (size_t)MF_MLP * KS_MLP * 64 * 4;
  int* meta = (int*)ws;
  // part2 (12 slices, 10.3 MB) aliases allx_h+allx_t (13.7 MB), dead after mlp.
  float* part2 = (float*)allx_h;

  ent_prep<<<B_ * E_, 256, 0, stream>>>(attn, hs, head, tail, ent_att, ent_feat);
  pair_att<<<L_, 256, 0, stream>>>(ent_att, mask, head, tail, etyp, ht_att, meta);
  pack_hs<<<(B_ * KS_HTI * 48 * 64) / 256, 256, 0, stream>>>(hs, hsPack);
  htinfo_mfma<<<dim3(9, 12, B_), 256, 0, stream>>>(ht_att, hsPack, ht_info);
  pack_Wmlp<<<dim3((KS_MLP * 48 * 64) / 256, 2), 256, 0, stream>>>(Wh, Wt, Wpack_h, Wpack_t);
  pack_allx<<<(2 * MF_MLP * KS_MLP * 64) / 256, 256, 0, stream>>>(
      ent_feat, ht_info, ttab, dtab, meta, allx_h, allx_t);
  mlp_mfma<<<dim3(35, 12, 2), 256, 0, stream>>>(allx_h, allx_t,
      Wpack_h, Wpack_t, bh, bt, h1, t1);
  pack_w<<<NB_ * 64, 256, 0, stream>>>(clsW, Wfrag);
  bilinear_mfma<<<432, 128, 0, stream>>>(h1, t1, Wfrag, part, part2);
  reduce_logits<<<(L_ * R_ + 255) / 256, 256, 0, stream>>>(part, part2, clsb, out);
}

// Round 12
// 127.502 us; speedup vs baseline: 1.1568x; 1.1568x over previous
//
#include <hip/hip_runtime.h>
#include <hip/hip_bf16.h>
#include <math.h>

#define B_ 4
#define S_ 512
#define H_ 768
#define NH_ 12
#define E_ 24
#define TE_ 20
#define TD_ 20
#define R_ 97
#define DIN_ 1576   // 2*H + TE + TD
#define KPAD_ 1600  // DIN padded to multiple of 32
#define KS_MLP 50   // KPAD/32
#define MF_MLP 140  // 2240/16 m-frags
#define KS_HTI 16   // 512/32
#define P_ 552      // E*(E-1)
#define L_ 2208     // B*P
#define NB_ 12      // H/64
#define NF_ 7       // n-frags of 16 cols covering 97 -> 112

typedef __bf16 bf16x8 __attribute__((ext_vector_type(8)));
typedef float f32x4 __attribute__((ext_vector_type(4)));

__device__ __forceinline__ unsigned short f2bf(float f) {
  union { float f; unsigned u; } c; c.f = f;
  unsigned r = c.u + 0x7FFF + ((c.u >> 16) & 1);
  return (unsigned short)(r >> 16);
}
__device__ __forceinline__ float bf2f(unsigned short b) {
  union { unsigned u; float f; } c; c.u = ((unsigned)b) << 16;
  return c.f;
}
__device__ __forceinline__ unsigned pk2(float a, float b) {
  return (unsigned)f2bf(a) | ((unsigned)f2bf(b) << 16);
}
// async global->LDS, 16B per lane; LDS dest = wave-uniform base + lane*16
__device__ __forceinline__ void gload_lds16(const uint4* g, uint4* l) {
  __builtin_amdgcn_global_load_lds(
      (const __attribute__((address_space(1))) unsigned*)(const void*)g,
      (__attribute__((address_space(3))) unsigned*)(void*)l, 16, 0, 0);
}

// ---------------------------------------------------------------------------
// K1: per-entity gathered attention-row sum over heads + entity features.
// ---------------------------------------------------------------------------
__global__ void ent_prep(const float* __restrict__ attn, const float* __restrict__ hs,
                         const int* __restrict__ head, const int* __restrict__ tail,
                         float* __restrict__ ent_att, float* __restrict__ ent_feat) {
  int be = blockIdx.x;
  int b = be / E_;
  int hd = head[be], tl = tail[be];
  int tid = threadIdx.x;
  const float* abase = attn + (size_t)b * NH_ * S_ * S_;
  for (int s = tid; s < S_; s += 256) {
    float acc = 0.f;
#pragma unroll
    for (int nh = 0; nh < NH_; ++nh) {
      const float* ap = abase + (size_t)nh * S_ * S_;
      acc += ap[(size_t)hd * S_ + s] + ap[(size_t)tl * S_ + s];
    }
    ent_att[(size_t)be * S_ + s] = 0.5f * acc;
  }
  const float* hb = hs + (size_t)b * S_ * H_;
  for (int k = tid; k < H_; k += 256) {
    ent_feat[(size_t)be * H_ + k] = 0.5f * (hb[(size_t)hd * H_ + k] + hb[(size_t)tl * H_ + k]);
  }
}

// ---------------------------------------------------------------------------
// K2: pairwise attention product + mask + normalize; pair metadata.
// ---------------------------------------------------------------------------
__global__ void pair_att(const float* __restrict__ ent_att, const float* __restrict__ mask,
                         const int* __restrict__ head, const int* __restrict__ tail,
                         const int* __restrict__ etype,
                         float* __restrict__ ht_att, int* __restrict__ meta) {
  int l = blockIdx.x;
  int b = l / P_, p = l % P_;
  int i0 = p / (E_ - 1), rem = p % (E_ - 1);
  int i1 = rem + (rem >= i0 ? 1 : 0);
  int tid = threadIdx.x;
  if (tid == 0) {
    meta[0 * L_ + l] = b * E_ + i0;
    meta[1 * L_ + l] = b * E_ + i1;
    meta[2 * L_ + l] = etype[b * E_ + i0];
    meta[3 * L_ + l] = etype[b * E_ + i1];
    int d = abs(tail[b * E_ + i0] - head[b * E_ + i1]);
    int bk = (d >= 2) + (d >= 4) + (d >= 8) + (d >= 16) + (d >= 32) +
             (d >= 64) + (d >= 128) + (d >= 256) + (d >= 512);
    meta[4 * L_ + l] = bk;
  }
  const float* a0 = ent_att + (size_t)(b * E_ + i0) * S_;
  const float* a1 = ent_att + (size_t)(b * E_ + i1) * S_;
  const float* m = mask + (size_t)b * S_;
  float v0 = a0[tid] * a1[tid] * m[tid];
  float v1 = a0[tid + 256] * a1[tid + 256] * m[tid + 256];
  float loc = v0 + v1;
  for (int o = 32; o > 0; o >>= 1) loc += __shfl_down(loc, o, 64);
  __shared__ float red[4];
  if ((tid & 63) == 0) red[tid >> 6] = loc;
  __syncthreads();
  float tot = red[0] + red[1] + red[2] + red[3];
  float inv = 1.f / (tot + 1e-20f);
  ht_att[(size_t)l * S_ + tid] = v0 * inv;
  ht_att[(size_t)l * S_ + tid + 256] = v1 * inv;
}

// ---------------------------------------------------------------------------
// pack_hs: hs (B,S,H f32) -> bf16 fragment-major [b][ks][nt16(48)][lane][8]
// ---------------------------------------------------------------------------
__global__ void pack_hs(const float* __restrict__ hs, uint4* __restrict__ hsP) {
  int u = blockIdx.x * 256 + threadIdx.x;
  if (u >= B_ * KS_HTI * 48 * 64) return;
  int lane = u & 63;
  int t = u >> 6;
  int nt16 = t % 48;
  int t2 = t / 48;
  int ks = t2 % KS_HTI;
  int b = t2 / KS_HTI;
  int n = nt16 * 16 + (lane & 15);
  int k0 = ks * 32 + ((lane >> 4) << 3);
  const float* src = hs + (size_t)b * S_ * H_;
  unsigned w[4];
#pragma unroll
  for (int q = 0; q < 4; ++q) {
    int k = k0 + 2 * q;
    w[q] = pk2(src[(size_t)k * H_ + n], src[(size_t)(k + 1) * H_ + n]);
  }
  uint4 o; o.x = w[0]; o.y = w[1]; o.z = w[2]; o.w = w[3];
  hsP[u] = o;
}

// ---------------------------------------------------------------------------
// pack_Wmlp: Wh/Wt (DIN,H f32) -> bf16 fragment-major [ks][nt16(48)][lane][8]
// ---------------------------------------------------------------------------
__global__ void pack_Wmlp(const float* __restrict__ Wh, const float* __restrict__ Wt,
                          uint4* __restrict__ WpH, uint4* __restrict__ WpT) {
  int u = blockIdx.x * 256 + threadIdx.x;
  if (u >= KS_MLP * 48 * 64) return;
  const float* W = blockIdx.y ? Wt : Wh;
  uint4* Wp = blockIdx.y ? WpT : WpH;
  int lane = u & 63;
  int t = u >> 6;
  int nt16 = t % 48;
  int ks = t / 48;
  int n = nt16 * 16 + (lane & 15);
  int k0 = ks * 32 + ((lane >> 4) << 3);
  unsigned w[4];
#pragma unroll
  for (int q = 0; q < 4; ++q) {
    int k = k0 + 2 * q;
    float v0 = (k < DIN_) ? W[(size_t)k * H_ + n] : 0.f;
    float v1 = (k + 1 < DIN_) ? W[(size_t)(k + 1) * H_ + n] : 0.f;
    w[q] = pk2(v0, v1);
  }
  uint4 o; o.x = w[0]; o.y = w[1]; o.z = w[2]; o.w = w[3];
  Wp[u] = o;
}

// ---------------------------------------------------------------------------
// pack_allx: gathered A matrices (all_h / all_t) in bf16 frag-major
// [mf(140)][ks(50)][lane][8].
// ---------------------------------------------------------------------------
__global__ void pack_allx(const float* __restrict__ ent_feat, const float* __restrict__ ht_info,
                          const float* __restrict__ ttab, const float* __restrict__ dtab,
                          const int* __restrict__ meta,
                          uint4* __restrict__ axH, uint4* __restrict__ axT) {
  int idx = blockIdx.x * 256 + threadIdx.x;   // 2*7000*64 = 896000 exact
  int lane = idx & 63;
  int unit = idx >> 6;
  int half = unit / (MF_MLP * KS_MLP);
  int rem = unit % (MF_MLP * KS_MLP);
  int mf = rem / KS_MLP, ks = rem % KS_MLP;
  int row = mf * 16 + (lane & 15);
  int k = ks * 32 + ((lane >> 4) << 3);
  uint4 d; d.x = d.y = d.z = d.w = 0;
  if (row < L_) {
    int frow = meta[half * L_ + row];
    int trow = meta[(2 + half) * L_ + row];
    int db = meta[4 * L_ + row];
    if (k < 768) {
      const float* p = ent_feat + (size_t)frow * H_ + k;
      float4 v0 = *(const float4*)p, v1 = *(const float4*)(p + 4);
      d.x = pk2(v0.x, v0.y); d.y = pk2(v0.z, v0.w);
      d.z = pk2(v1.x, v1.y); d.w = pk2(v1.z, v1.w);
    } else if (k < 1536) {
      const float* p = ht_info + (size_t)row * H_ + (k - 768);
      float4 v0 = *(const float4*)p, v1 = *(const float4*)(p + 4);
      d.x = pk2(v0.x, v0.y); d.y = pk2(v0.z, v0.w);
      d.z = pk2(v1.x, v1.y); d.w = pk2(v1.z, v1.w);
    } else {
      float v[8];
#pragma unroll
      for (int j = 0; j < 8; ++j) {
        int e = k + j;
        v[j] = (e < 1556) ? ttab[trow * TE_ + (e - 1536)]
             : (e < 1576) ? dtab[db * TD_ + (e - 1556)] : 0.f;
      }
      d.x = pk2(v[0], v[1]); d.y = pk2(v[2], v[3]);
      d.z = pk2(v[4], v[5]); d.w = pk2(v[6], v[7]);
    }
  }
  (half ? axT : axH)[(size_t)rem * 64 + lane] = d;
}

// ---------------------------------------------------------------------------
// htinfo_mfma v3: BM=64 BN=64 BK=64, 8 K-steps, 4 waves (2m x 2n).
// ---------------------------------------------------------------------------
__global__ __launch_bounds__(256) void htinfo_mfma(
    const float* __restrict__ htatt, const uint4* __restrict__ hsP,
    float* __restrict__ htinfo) {
  int b = blockIdx.z;
  int m0 = blockIdx.x * 64;
  int nt0 = blockIdx.y * 4;
  int tid = threadIdx.x;
  int wave = tid >> 6, lane = tid & 63;
  int wm = wave & 1, wn = wave >> 1;
  __shared__ __align__(16) uint4 Ash[2][512];
  __shared__ __align__(16) uint4 Bsh[2][512];

  f32x4 acc[2][2];
#pragma unroll
  for (int i = 0; i < 2; ++i)
#pragma unroll
    for (int j = 0; j < 2; ++j) acc[i][j] = (f32x4){0.f, 0.f, 0.f, 0.f};

  auto stageB = [&](int s, int buf) {
#pragma unroll
    for (int i = 0; i < 2; ++i) {
      int c = wave * 2 + i;
      int ntl = c >> 1, kslot = c & 1;
      gload_lds16(hsP + ((size_t)(b * KS_HTI + s * 2 + kslot) * 48 + nt0 + ntl) * 64 + lane,
                  &Bsh[buf][c * 64]);
    }
  };
  auto gatherA = [&](int s, int c, uint4& d) {
    int mfl = c >> 1, kslot = c & 1;
    int row = m0 + mfl * 16 + (lane & 15);
    if (row >= P_) { d.x = d.y = d.z = d.w = 0; return; }
    int k = s * 64 + kslot * 32 + ((lane >> 4) << 3);
    const float* p = htatt + ((size_t)b * P_ + row) * S_ + k;
    float4 v0 = *(const float4*)p, v1 = *(const float4*)(p + 4);
    d.x = pk2(v0.x, v0.y); d.y = pk2(v0.z, v0.w);
    d.z = pk2(v1.x, v1.y); d.w = pk2(v1.z, v1.w);
  };

  {
    uint4 a0_, a1_;
    gatherA(0, wave, a0_); gatherA(0, wave + 4, a1_);
    Ash[0][wave * 64 + lane] = a0_;
    Ash[0][(wave + 4) * 64 + lane] = a1_;
    stageB(0, 0);
  }
  __syncthreads();

  for (int s = 0; s < 8; ++s) {
    int cur = s & 1, nxt = cur ^ 1;
    bool more = (s + 1 < 8);
    uint4 aN0, aN1;
    if (more) {
      stageB(s + 1, nxt);
      gatherA(s + 1, wave, aN0); gatherA(s + 1, wave + 4, aN1);
    }
    bf16x8 af[2][2], bf[2][2];
#pragma unroll
    for (int mf = 0; mf < 2; ++mf)
#pragma unroll
      for (int kc = 0; kc < 2; ++kc)
        af[mf][kc] = *(const bf16x8*)&Ash[cur][((wm * 2 + mf) * 2 + kc) * 64 + lane];
#pragma unroll
    for (int nf = 0; nf < 2; ++nf)
#pragma unroll
      for (int kc = 0; kc < 2; ++kc)
        bf[nf][kc] = *(const bf16x8*)&Bsh[cur][((wn * 2 + nf) * 2 + kc) * 64 + lane];
#pragma unroll
    for (int kc = 0; kc < 2; ++kc)
#pragma unroll
      for (int nf = 0; nf < 2; ++nf)
#pragma unroll
        for (int mf = 0; mf < 2; ++mf)
          acc[mf][nf] = __builtin_amdgcn_mfma_f32_16x16x32_bf16(af[mf][kc], bf[nf][kc], acc[mf][nf], 0, 0, 0);
    if (more) {
      Ash[nxt][wave * 64 + lane] = aN0;
      Ash[nxt][(wave + 4) * 64 + lane] = aN1;
    }
    __syncthreads();
  }

#pragma unroll
  for (int mf = 0; mf < 2; ++mf)
#pragma unroll
    for (int nf = 0; nf < 2; ++nf) {
      int n = nt0 * 16 + (wn * 2 + nf) * 16 + (lane & 15);
#pragma unroll
      for (int reg = 0; reg < 4; ++reg) {
        int l = m0 + (wm * 2 + mf) * 16 + ((lane >> 4) << 2) + reg;
        if (l < P_)
          htinfo[((size_t)b * P_ + l) * H_ + n] = acc[mf][nf][reg];
      }
    }
}

// ---------------------------------------------------------------------------
// mlp_mfma v3 (reverted to R6 structure): pure GEMM, dbuf + syncthreads.
// ---------------------------------------------------------------------------
__global__ __launch_bounds__(256) void mlp_mfma(
    const uint4* __restrict__ Apk_h, const uint4* __restrict__ Apk_t,
    const uint4* __restrict__ Wp_h, const uint4* __restrict__ Wp_t,
    const float* __restrict__ bh, const float* __restrict__ bt,
    float* __restrict__ h1, float* __restrict__ t1) {
  int half = blockIdx.z;
  const uint4* Apk = half ? Apk_t : Apk_h;
  const uint4* Wp = half ? Wp_t : Wp_h;
  const float* bias = half ? bt : bh;
  float* out = half ? t1 : h1;
  int mf0 = blockIdx.x * 4;
  int nt0 = blockIdx.y * 4;
  int tid = threadIdx.x;
  int wave = tid >> 6, lane = tid & 63;
  int wm = wave & 1, wn = wave >> 1;
  __shared__ __align__(16) uint4 Ash[2][512];
  __shared__ __align__(16) uint4 Bsh[2][512];

  f32x4 acc[2][2];
#pragma unroll
  for (int i = 0; i < 2; ++i)
#pragma unroll
    for (int j = 0; j < 2; ++j) acc[i][j] = (f32x4){0.f, 0.f, 0.f, 0.f};

  auto stage = [&](int s, int buf) {
#pragma unroll
    for (int i = 0; i < 2; ++i) {
      int c = wave * 2 + i;
      int cl = c >> 1, kslot = c & 1;
      gload_lds16(Apk + ((size_t)(mf0 + cl) * KS_MLP + s * 2 + kslot) * 64 + lane,
                  &Ash[buf][c * 64]);
      gload_lds16(Wp + ((size_t)(s * 2 + kslot) * 48 + nt0 + cl) * 64 + lane,
                  &Bsh[buf][c * 64]);
    }
  };

  stage(0, 0);
  __syncthreads();

  for (int s = 0; s < 25; ++s) {
    int cur = s & 1, nxt = cur ^ 1;
    if (s + 1 < 25) stage(s + 1, nxt);
    bf16x8 af[2][2], bf[2][2];
#pragma unroll
    for (int mf = 0; mf < 2; ++mf)
#pragma unroll
      for (int kc = 0; kc < 2; ++kc)
        af[mf][kc] = *(const bf16x8*)&Ash[cur][((wm * 2 + mf) * 2 + kc) * 64 + lane];
#pragma unroll
    for (int nf = 0; nf < 2; ++nf)
#pragma unroll
      for (int kc = 0; kc < 2; ++kc)
        bf[nf][kc] = *(const bf16x8*)&Bsh[cur][((wn * 2 + nf) * 2 + kc) * 64 + lane];
#pragma unroll
    for (int kc = 0; kc < 2; ++kc)
#pragma unroll
      for (int nf = 0; nf < 2; ++nf)
#pragma unroll
        for (int mf = 0; mf < 2; ++mf)
          acc[mf][nf] = __builtin_amdgcn_mfma_f32_16x16x32_bf16(af[mf][kc], bf[nf][kc], acc[mf][nf], 0, 0, 0);
    __syncthreads();
  }

#pragma unroll
  for (int mf = 0; mf < 2; ++mf)
#pragma unroll
    for (int nf = 0; nf < 2; ++nf) {
      int n = nt0 * 16 + (wn * 2 + nf) * 16 + (lane & 15);
      float bv = bias[n];
#pragma unroll
      for (int reg = 0; reg < 4; ++reg) {
        int l = (mf0 + wm * 2 + mf) * 16 + ((lane >> 4) << 2) + reg;
        if (l < L_)
          out[(size_t)l * H_ + n] = tanhf(acc[mf][nf][reg] + bv);
      }
    }
}

// ---------------------------------------------------------------------------
// K5a: pre-pack clsW -> fragment-major bf16 for the bilinear B-operand.
// ---------------------------------------------------------------------------
__global__ void pack_w(const float* __restrict__ clsW, uint4* __restrict__ Wfrag) {
  int nb = blockIdx.x;            // n*64 + b
  __shared__ float Wls[64][98];
  int tid = threadIdx.x;
  const float* src = clsW + (size_t)nb * 64 * R_;
  for (int idx = tid; idx < 64 * R_; idx += 256) {
    Wls[idx / R_][idx % R_] = src[idx];
  }
  __syncthreads();
  for (int u = tid; u < 896; u += 256) {
    int nf = u >> 7;
    int kc = (u >> 6) & 1;
    int lane = u & 63;
    int r = (lane & 15) + 16 * nf;
    unsigned w[4];
#pragma unroll
    for (int q = 0; q < 4; ++q) {
      int c0 = ((lane >> 4) << 3) + 2 * q + 32 * kc;
      float v0 = (r < R_) ? Wls[c0][r] : 0.f;
      float v1 = (r < R_) ? Wls[c0 + 1][r] : 0.f;
      w[q] = (unsigned)f2bf(v0) | ((unsigned)f2bf(v1) << 16);
    }
    uint4 o; o.x = w[0]; o.y = w[1]; o.z = w[2]; o.w = w[3];
    Wfrag[(size_t)nb * 896 + u] = o;
  }
}

// ---------------------------------------------------------------------------
// K5b v8: bilinear MFMA tuned for TLP. 864 blocks x 4 waves = 13.5 waves/CU
// all-resident (LDS 37KB -> 4 blocks/CU). Waves: wm (m-half, 32 rows each,
// mf=2) x kh (in-block K-split: 16 b's each). BK=32 (half-b per step), 32
// steps, simple dbuf + syncthreads (m97 pattern; TLP hides the drain).
// XCD decode keeps each (n,z) pair's Wfrag slice on one XCD L2.
// ---------------------------------------------------------------------------
__global__ __launch_bounds__(256) void bilinear_mfma(
    const float* __restrict__ h1, const float* __restrict__ t1,
    const uint4* __restrict__ Wfrag, float* __restrict__ part,
    float* __restrict__ part2) {
  int blk = blockIdx.x;
  int xcd = blk & 7;
  int slot = blk >> 3;        // 0..107
  int pg = slot / 36;         // 0..2
  int j = slot % 36;          // l-tile index (64 rows)
  int p = pg * 8 + xcd;       // 0..23
  int n = p >> 1, z = p & 1;
  int l0 = j * 64;
  int tid = threadIdx.x;
  int wave = tid >> 6, lane = tid & 63;
  int wm = wave & 1, kh = wave >> 1;
  __shared__ __align__(16) uint4 Wl[2][2][7][64];   // [kh][dbuf][nf][lane] 28672 B
  __shared__ unsigned short x1s[32][66];            // [b_local][row], padded

  // x1 tile (32 b's for this z, 64 rows) -> LDS transposed, bf16
  for (int i = tid; i < 512; i += 256) {
    int row = i >> 3, cq = (i & 7) * 4;
    float4 v = make_float4(0, 0, 0, 0);
    if (l0 + row < L_)
      v = *(const float4*)(h1 + (size_t)(l0 + row) * H_ + n * 64 + z * 32 + cq);
    x1s[cq + 0][row] = f2bf(v.x);
    x1s[cq + 1][row] = f2bf(v.y);
    x1s[cq + 2][row] = f2bf(v.z);
    x1s[cq + 3][row] = f2bf(v.w);
  }

  // x2 fragments (b-invariant): 2 m-frags x 2 kc x 8 f32
  float x2f[2][2][8];
#pragma unroll
  for (int mf = 0; mf < 2; ++mf) {
    int row = l0 + wm * 32 + mf * 16 + (lane & 15);
#pragma unroll
    for (int kc = 0; kc < 2; ++kc) {
      float4 v0 = make_float4(0, 0, 0, 0), v1 = v0;
      if (row < L_) {
        const float* ptr = t1 + (size_t)row * H_ + n * 64 + kc * 32 + ((lane >> 4) << 3);
        v0 = *(const float4*)ptr;
        v1 = *(const float4*)(ptr + 4);
      }
      x2f[mf][kc][0] = v0.x; x2f[mf][kc][1] = v0.y;
      x2f[mf][kc][2] = v0.z; x2f[mf][kc][3] = v0.w;
      x2f[mf][kc][4] = v1.x; x2f[mf][kc][5] = v1.y;
      x2f[mf][kc][6] = v1.z; x2f[mf][kc][7] = v1.w;
    }
  }

  f32x4 acc[2][NF_];
#pragma unroll
  for (int mf = 0; mf < 2; ++mf)
#pragma unroll
    for (int nf = 0; nf < NF_; ++nf)
      acc[mf][nf] = (f32x4){0.f, 0.f, 0.f, 0.f};

  const uint4* gbase = Wfrag + (size_t)n * 64 * 896;
  // stage step s for this kh-group: b = z*32 + kh*16 + (s>>1), kc = s&1;
  // 7 chunks of 1KB: wm=0 stages nf 0..3, wm=1 stages nf 4..6.
  auto stage = [&](int s, int buf) {
    int b = z * 32 + kh * 16 + (s >> 1);
    int kc = s & 1;
    const uint4* gs = gbase + (size_t)b * 896 + kc * 64 + lane;
    if (wm == 0) {
#pragma unroll
      for (int nf = 0; nf < 4; ++nf)
        gload_lds16(gs + nf * 128, &Wl[kh][buf][nf][0]);
    } else {
#pragma unroll
      for (int nf = 4; nf < 7; ++nf)
        gload_lds16(gs + nf * 128, &Wl[kh][buf][nf][0]);
    }
  };

  stage(0, 0);
  __syncthreads();

  for (int s = 0; s < 32; ++s) {
    int cur = s & 1, nxt = cur ^ 1;
    if (s + 1 < 32) stage(s + 1, nxt);
    int bl = kh * 16 + (s >> 1);   // x1s row for this wave's b
    int kc = s & 1;
    bf16x8 afr[2];
#pragma unroll
    for (int mf = 0; mf < 2; ++mf) {
      float x1v = bf2f(x1s[bl][wm * 32 + mf * 16 + (lane & 15)]);
#pragma unroll
      for (int jj = 0; jj < 8; ++jj)
        afr[mf][jj] = (__bf16)(x1v * x2f[mf][kc][jj]);
    }
#pragma unroll
    for (int nf = 0; nf < NF_; ++nf) {
      bf16x8 bfr = *(const bf16x8*)&Wl[kh][cur][nf][lane];
#pragma unroll
      for (int mf = 0; mf < 2; ++mf)
        acc[mf][nf] = __builtin_amdgcn_mfma_f32_16x16x32_bf16(
            afr[mf], bfr, acc[mf][nf], 0, 0, 0);
    }
    __syncthreads();
  }

  // kh-reduction via LDS (reuse Wl: 7168 floats = exactly 128 x 56)
  float* red = (float*)&Wl[0][0][0][0];
  int rbase = (wm * 64 + lane) * 56;
  if (kh == 1) {
#pragma unroll
    for (int mf = 0; mf < 2; ++mf)
#pragma unroll
      for (int nf = 0; nf < NF_; ++nf)
        *(f32x4*)&red[rbase + (mf * NF_ + nf) * 4] = acc[mf][nf];
  }
  __syncthreads();
  if (kh == 0) {
    float* dst = (z == 0) ? part : part2;
#pragma unroll
    for (int mf = 0; mf < 2; ++mf) {
#pragma unroll
      for (int nf = 0; nf < NF_; ++nf) {
        acc[mf][nf] += *(const f32x4*)&red[rbase + (mf * NF_ + nf) * 4];
        int r = nf * 16 + (lane & 15);
        if (r < R_) {
#pragma unroll
          for (int reg = 0; reg < 4; ++reg) {
            int l = l0 + wm * 32 + mf * 16 + ((lane >> 4) << 2) + reg;
            if (l < L_)
              dst[((size_t)n * L_ + l) * R_ + r] = acc[mf][nf][reg];
          }
        }
      }
    }
  }
}

// ---------------------------------------------------------------------------
// K6: reduce 24 partial slices (12 in part, 12 in part2), add clsb.
// ---------------------------------------------------------------------------
__global__ void reduce_logits(const float* __restrict__ part, const float* __restrict__ part2,
                              const float* __restrict__ clsb, float* __restrict__ out) {
  int idx = blockIdx.x * 256 + threadIdx.x;
  if (idx < L_ * R_) {
    int r = idx % R_;
    float s = clsb[r];
#pragma unroll
    for (int nn = 0; nn < NB_; ++nn)
      s += part[(size_t)nn * L_ * R_ + idx] + part2[(size_t)nn * L_ * R_ + idx];
    out[idx] = s;
  }
}

extern "C" void kernel_launch(void* const* d_in, const int* in_sizes, int n_in,
                              void* d_out, int out_size, void* d_ws, size_t ws_size,
                              hipStream_t stream) {
  const float* hs   = (const float*)d_in[0];
  const float* attn = (const float*)d_in[1];
  const float* mask = (const float*)d_in[2];
  const int*   head = (const int*)d_in[3];
  const int*   tail = (const int*)d_in[4];
  const int*   etyp = (const int*)d_in[5];
  const float* ttab = (const float*)d_in[6];
  const float* dtab = (const float*)d_in[7];
  const float* Wh   = (const float*)d_in[8];
  const float* bh   = (const float*)d_in[9];
  const float* Wt   = (const float*)d_in[10];
  const float* bt   = (const float*)d_in[11];
  const float* clsW = (const float*)d_in[12];
  const float* clsb = (const float*)d_in[13];
  float* out = (float*)d_out;

  float* ws = (float*)d_ws;
  float* ent_att  = ws; ws += (size_t)B_ * E_ * S_;
  float* ent_feat = ws; ws += (size_t)B_ * E_ * H_;
  float* ht_att   = ws; ws += (size_t)L_ * S_;
  float* ht_info  = ws; ws += (size_t)L_ * H_;
  float* h1       = ws; ws += (size_t)L_ * H_;
  float* t1       = ws; ws += (size_t)L_ * H_;
  float* part     = ws; ws += (size_t)NB_ * L_ * R_;
  uint4* Wpack_h  = (uint4*)ws; ws += (size_t)KS_MLP * 48 * 64 * 4;
  uint4* Wpack_t  = (uint4*)ws; ws += (size_t)KS_MLP * 48 * 64 * 4;
  uint4* hsPack   = (uint4*)ws; ws += (size_t)B_ * KS_HTI * 48 * 64 * 4;
  uint4* Wfrag    = (uint4*)ws; ws += (size_t)NB_ * 64 * 896 * 4;
  uint4* allx_h   = (uint4*)ws; ws += (size_t)MF_MLP * KS_MLP * 64 * 4;
  uint4* allx_t   = (uint4*)ws; ws += (size_t)MF_MLP * KS_MLP * 64 * 4;
  int* meta = (int*)ws;
  // part2 (12 slices, 10.3 MB) aliases allx_h+allx_t (13.7 MB), dead after mlp.
  float* part2 = (float*)allx_h;

  ent_prep<<<B_ * E_, 256, 0, stream>>>(attn, hs, head, tail, ent_att, ent_feat);
  pair_att<<<L_, 256, 0, stream>>>(ent_att, mask, head, tail, etyp, ht_att, meta);
  pack_hs<<<(B_ * KS_HTI * 48 * 64) / 256, 256, 0, stream>>>(hs, hsPack);
  htinfo_mfma<<<dim3(9, 12, B_), 256, 0, stream>>>(ht_att, hsPack, ht_info);
  pack_Wmlp<<<dim3((KS_MLP * 48 * 64) / 256, 2), 256, 0, stream>>>(Wh, Wt, Wpack_h, Wpack_t);
  pack_allx<<<(2 * MF_MLP * KS_MLP * 64) / 256, 256, 0, stream>>>(
      ent_feat, ht_info, ttab, dtab, meta, allx_h, allx_t);
  mlp_mfma<<<dim3(35, 12, 2), 256, 0, stream>>>(allx_h, allx_t,
      Wpack_h, Wpack_t, bh, bt, h1, t1);
  pack_w<<<NB_ * 64, 256, 0, stream>>>(clsW, Wfrag);
  bilinear_mfma<<<864, 256, 0, stream>>>(h1, t1, Wfrag, part, part2);
  reduce_logits<<<(L_ * R_ + 255) / 256, 256, 0, stream>>>(part, part2, clsb, out);
}

// Round 13
// 126.303 us; speedup vs baseline: 1.1677x; 1.0095x over previous
//
#include <hip/hip_runtime.h>
#include <hip/hip_bf16.h>
#include <math.h>

#define B_ 4
#define S_ 512
#define H_ 768
#define NH_ 12
#define E_ 24
#define TE_ 20
#define TD_ 20
#define R_ 97
#define DIN_ 1576   // 2*H + TE + TD
#define KPAD_ 1600  // DIN padded to multiple of 32
#define KS_MLP 50   // KPAD/32
#define MF_MLP 140  // 2240/16 m-frags
#define KS_HTI 16   // 512/32
#define P_ 552      // E*(E-1)
#define L_ 2208     // B*P
#define NB_ 12      // H/64
#define NF_ 7       // n-frags of 16 cols covering 97 -> 112

typedef __bf16 bf16x8 __attribute__((ext_vector_type(8)));
typedef float f32x4 __attribute__((ext_vector_type(4)));

__device__ __forceinline__ unsigned short f2bf(float f) {
  union { float f; unsigned u; } c; c.f = f;
  unsigned r = c.u + 0x7FFF + ((c.u >> 16) & 1);
  return (unsigned short)(r >> 16);
}
__device__ __forceinline__ float bf2f(unsigned short b) {
  union { unsigned u; float f; } c; c.u = ((unsigned)b) << 16;
  return c.f;
}
__device__ __forceinline__ unsigned pk2(float a, float b) {
  return (unsigned)f2bf(a) | ((unsigned)f2bf(b) << 16);
}
// async global->LDS, 16B per lane; LDS dest = wave-uniform base + lane*16
__device__ __forceinline__ void gload_lds16(const uint4* g, uint4* l) {
  __builtin_amdgcn_global_load_lds(
      (const __attribute__((address_space(1))) unsigned*)(const void*)g,
      (__attribute__((address_space(3))) unsigned*)(void*)l, 16, 0, 0);
}

// ---------------------------------------------------------------------------
// K1: per-entity gathered attention-row sum over heads + entity features.
// ---------------------------------------------------------------------------
__global__ void ent_prep(const float* __restrict__ attn, const float* __restrict__ hs,
                         const int* __restrict__ head, const int* __restrict__ tail,
                         float* __restrict__ ent_att, float* __restrict__ ent_feat) {
  int be = blockIdx.x;
  int b = be / E_;
  int hd = head[be], tl = tail[be];
  int tid = threadIdx.x;
  const float* abase = attn + (size_t)b * NH_ * S_ * S_;
  for (int s = tid; s < S_; s += 256) {
    float acc = 0.f;
#pragma unroll
    for (int nh = 0; nh < NH_; ++nh) {
      const float* ap = abase + (size_t)nh * S_ * S_;
      acc += ap[(size_t)hd * S_ + s] + ap[(size_t)tl * S_ + s];
    }
    ent_att[(size_t)be * S_ + s] = 0.5f * acc;
  }
  const float* hb = hs + (size_t)b * S_ * H_;
  for (int k = tid; k < H_; k += 256) {
    ent_feat[(size_t)be * H_ + k] = 0.5f * (hb[(size_t)hd * H_ + k] + hb[(size_t)tl * H_ + k]);
  }
}

// ---------------------------------------------------------------------------
// K2: pairwise attention product + mask + normalize; pair metadata.
// ---------------------------------------------------------------------------
__global__ void pair_att(const float* __restrict__ ent_att, const float* __restrict__ mask,
                         const int* __restrict__ head, const int* __restrict__ tail,
                         const int* __restrict__ etype,
                         float* __restrict__ ht_att, int* __restrict__ meta) {
  int l = blockIdx.x;
  int b = l / P_, p = l % P_;
  int i0 = p / (E_ - 1), rem = p % (E_ - 1);
  int i1 = rem + (rem >= i0 ? 1 : 0);
  int tid = threadIdx.x;
  if (tid == 0) {
    meta[0 * L_ + l] = b * E_ + i0;
    meta[1 * L_ + l] = b * E_ + i1;
    meta[2 * L_ + l] = etype[b * E_ + i0];
    meta[3 * L_ + l] = etype[b * E_ + i1];
    int d = abs(tail[b * E_ + i0] - head[b * E_ + i1]);
    int bk = (d >= 2) + (d >= 4) + (d >= 8) + (d >= 16) + (d >= 32) +
             (d >= 64) + (d >= 128) + (d >= 256) + (d >= 512);
    meta[4 * L_ + l] = bk;
  }
  const float* a0 = ent_att + (size_t)(b * E_ + i0) * S_;
  const float* a1 = ent_att + (size_t)(b * E_ + i1) * S_;
  const float* m = mask + (size_t)b * S_;
  float v0 = a0[tid] * a1[tid] * m[tid];
  float v1 = a0[tid + 256] * a1[tid + 256] * m[tid + 256];
  float loc = v0 + v1;
  for (int o = 32; o > 0; o >>= 1) loc += __shfl_down(loc, o, 64);
  __shared__ float red[4];
  if ((tid & 63) == 0) red[tid >> 6] = loc;
  __syncthreads();
  float tot = red[0] + red[1] + red[2] + red[3];
  float inv = 1.f / (tot + 1e-20f);
  ht_att[(size_t)l * S_ + tid] = v0 * inv;
  ht_att[(size_t)l * S_ + tid + 256] = v1 * inv;
}

// ---------------------------------------------------------------------------
// pack_hs: hs (B,S,H f32) -> bf16 fragment-major [b][ks][nt16(48)][lane][8]
// ---------------------------------------------------------------------------
__global__ void pack_hs(const float* __restrict__ hs, uint4* __restrict__ hsP) {
  int u = blockIdx.x * 256 + threadIdx.x;
  if (u >= B_ * KS_HTI * 48 * 64) return;
  int lane = u & 63;
  int t = u >> 6;
  int nt16 = t % 48;
  int t2 = t / 48;
  int ks = t2 % KS_HTI;
  int b = t2 / KS_HTI;
  int n = nt16 * 16 + (lane & 15);
  int k0 = ks * 32 + ((lane >> 4) << 3);
  const float* src = hs + (size_t)b * S_ * H_;
  unsigned w[4];
#pragma unroll
  for (int q = 0; q < 4; ++q) {
    int k = k0 + 2 * q;
    w[q] = pk2(src[(size_t)k * H_ + n], src[(size_t)(k + 1) * H_ + n]);
  }
  uint4 o; o.x = w[0]; o.y = w[1]; o.z = w[2]; o.w = w[3];
  hsP[u] = o;
}

// ---------------------------------------------------------------------------
// pack_Wmlp: Wh/Wt (DIN,H f32) -> bf16 fragment-major [ks][nt16(48)][lane][8]
// ---------------------------------------------------------------------------
__global__ void pack_Wmlp(const float* __restrict__ Wh, const float* __restrict__ Wt,
                          uint4* __restrict__ WpH, uint4* __restrict__ WpT) {
  int u = blockIdx.x * 256 + threadIdx.x;
  if (u >= KS_MLP * 48 * 64) return;
  const float* W = blockIdx.y ? Wt : Wh;
  uint4* Wp = blockIdx.y ? WpT : WpH;
  int lane = u & 63;
  int t = u >> 6;
  int nt16 = t % 48;
  int ks = t / 48;
  int n = nt16 * 16 + (lane & 15);
  int k0 = ks * 32 + ((lane >> 4) << 3);
  unsigned w[4];
#pragma unroll
  for (int q = 0; q < 4; ++q) {
    int k = k0 + 2 * q;
    float v0 = (k < DIN_) ? W[(size_t)k * H_ + n] : 0.f;
    float v1 = (k + 1 < DIN_) ? W[(size_t)(k + 1) * H_ + n] : 0.f;
    w[q] = pk2(v0, v1);
  }
  uint4 o; o.x = w[0]; o.y = w[1]; o.z = w[2]; o.w = w[3];
  Wp[u] = o;
}

// ---------------------------------------------------------------------------
// pack_allx: gathered A matrices (all_h / all_t) in bf16 frag-major
// [mf(140)][ks(50)][lane][8].
// ---------------------------------------------------------------------------
__global__ void pack_allx(const float* __restrict__ ent_feat, const float* __restrict__ ht_info,
                          const float* __restrict__ ttab, const float* __restrict__ dtab,
                          const int* __restrict__ meta,
                          uint4* __restrict__ axH, uint4* __restrict__ axT) {
  int idx = blockIdx.x * 256 + threadIdx.x;   // 2*7000*64 = 896000 exact
  int lane = idx & 63;
  int unit = idx >> 6;
  int half = unit / (MF_MLP * KS_MLP);
  int rem = unit % (MF_MLP * KS_MLP);
  int mf = rem / KS_MLP, ks = rem % KS_MLP;
  int row = mf * 16 + (lane & 15);
  int k = ks * 32 + ((lane >> 4) << 3);
  uint4 d; d.x = d.y = d.z = d.w = 0;
  if (row < L_) {
    int frow = meta[half * L_ + row];
    int trow = meta[(2 + half) * L_ + row];
    int db = meta[4 * L_ + row];
    if (k < 768) {
      const float* p = ent_feat + (size_t)frow * H_ + k;
      float4 v0 = *(const float4*)p, v1 = *(const float4*)(p + 4);
      d.x = pk2(v0.x, v0.y); d.y = pk2(v0.z, v0.w);
      d.z = pk2(v1.x, v1.y); d.w = pk2(v1.z, v1.w);
    } else if (k < 1536) {
      const float* p = ht_info + (size_t)row * H_ + (k - 768);
      float4 v0 = *(const float4*)p, v1 = *(const float4*)(p + 4);
      d.x = pk2(v0.x, v0.y); d.y = pk2(v0.z, v0.w);
      d.z = pk2(v1.x, v1.y); d.w = pk2(v1.z, v1.w);
    } else {
      float v[8];
#pragma unroll
      for (int j = 0; j < 8; ++j) {
        int e = k + j;
        v[j] = (e < 1556) ? ttab[trow * TE_ + (e - 1536)]
             : (e < 1576) ? dtab[db * TD_ + (e - 1556)] : 0.f;
      }
      d.x = pk2(v[0], v[1]); d.y = pk2(v[2], v[3]);
      d.z = pk2(v[4], v[5]); d.w = pk2(v[6], v[7]);
    }
  }
  (half ? axT : axH)[(size_t)rem * 64 + lane] = d;
}

// ---------------------------------------------------------------------------
// htinfo_mfma v3: BM=64 BN=64 BK=64, 8 K-steps, 4 waves (2m x 2n).
// ---------------------------------------------------------------------------
__global__ __launch_bounds__(256) void htinfo_mfma(
    const float* __restrict__ htatt, const uint4* __restrict__ hsP,
    float* __restrict__ htinfo) {
  int b = blockIdx.z;
  int m0 = blockIdx.x * 64;
  int nt0 = blockIdx.y * 4;
  int tid = threadIdx.x;
  int wave = tid >> 6, lane = tid & 63;
  int wm = wave & 1, wn = wave >> 1;
  __shared__ __align__(16) uint4 Ash[2][512];
  __shared__ __align__(16) uint4 Bsh[2][512];

  f32x4 acc[2][2];
#pragma unroll
  for (int i = 0; i < 2; ++i)
#pragma unroll
    for (int j = 0; j < 2; ++j) acc[i][j] = (f32x4){0.f, 0.f, 0.f, 0.f};

  auto stageB = [&](int s, int buf) {
#pragma unroll
    for (int i = 0; i < 2; ++i) {
      int c = wave * 2 + i;
      int ntl = c >> 1, kslot = c & 1;
      gload_lds16(hsP + ((size_t)(b * KS_HTI + s * 2 + kslot) * 48 + nt0 + ntl) * 64 + lane,
                  &Bsh[buf][c * 64]);
    }
  };
  auto gatherA = [&](int s, int c, uint4& d) {
    int mfl = c >> 1, kslot = c & 1;
    int row = m0 + mfl * 16 + (lane & 15);
    if (row >= P_) { d.x = d.y = d.z = d.w = 0; return; }
    int k = s * 64 + kslot * 32 + ((lane >> 4) << 3);
    const float* p = htatt + ((size_t)b * P_ + row) * S_ + k;
    float4 v0 = *(const float4*)p, v1 = *(const float4*)(p + 4);
    d.x = pk2(v0.x, v0.y); d.y = pk2(v0.z, v0.w);
    d.z = pk2(v1.x, v1.y); d.w = pk2(v1.z, v1.w);
  };

  {
    uint4 a0_, a1_;
    gatherA(0, wave, a0_); gatherA(0, wave + 4, a1_);
    Ash[0][wave * 64 + lane] = a0_;
    Ash[0][(wave + 4) * 64 + lane] = a1_;
    stageB(0, 0);
  }
  __syncthreads();

  for (int s = 0; s < 8; ++s) {
    int cur = s & 1, nxt = cur ^ 1;
    bool more = (s + 1 < 8);
    uint4 aN0, aN1;
    if (more) {
      stageB(s + 1, nxt);
      gatherA(s + 1, wave, aN0); gatherA(s + 1, wave + 4, aN1);
    }
    bf16x8 af[2][2], bf[2][2];
#pragma unroll
    for (int mf = 0; mf < 2; ++mf)
#pragma unroll
      for (int kc = 0; kc < 2; ++kc)
        af[mf][kc] = *(const bf16x8*)&Ash[cur][((wm * 2 + mf) * 2 + kc) * 64 + lane];
#pragma unroll
    for (int nf = 0; nf < 2; ++nf)
#pragma unroll
      for (int kc = 0; kc < 2; ++kc)
        bf[nf][kc] = *(const bf16x8*)&Bsh[cur][((wn * 2 + nf) * 2 + kc) * 64 + lane];
#pragma unroll
    for (int kc = 0; kc < 2; ++kc)
#pragma unroll
      for (int nf = 0; nf < 2; ++nf)
#pragma unroll
        for (int mf = 0; mf < 2; ++mf)
          acc[mf][nf] = __builtin_amdgcn_mfma_f32_16x16x32_bf16(af[mf][kc], bf[nf][kc], acc[mf][nf], 0, 0, 0);
    if (more) {
      Ash[nxt][wave * 64 + lane] = aN0;
      Ash[nxt][(wave + 4) * 64 + lane] = aN1;
    }
    __syncthreads();
  }

#pragma unroll
  for (int mf = 0; mf < 2; ++mf)
#pragma unroll
    for (int nf = 0; nf < 2; ++nf) {
      int n = nt0 * 16 + (wn * 2 + nf) * 16 + (lane & 15);
#pragma unroll
      for (int reg = 0; reg < 4; ++reg) {
        int l = m0 + (wm * 2 + mf) * 16 + ((lane >> 4) << 2) + reg;
        if (l < P_)
          htinfo[((size_t)b * P_ + l) * H_ + n] = acc[mf][nf][reg];
      }
    }
}

// ---------------------------------------------------------------------------
// mlp_mfma v3 (R6 structure): pure GEMM, dbuf + syncthreads.
// ---------------------------------------------------------------------------
__global__ __launch_bounds__(256) void mlp_mfma(
    const uint4* __restrict__ Apk_h, const uint4* __restrict__ Apk_t,
    const uint4* __restrict__ Wp_h, const uint4* __restrict__ Wp_t,
    const float* __restrict__ bh, const float* __restrict__ bt,
    float* __restrict__ h1, float* __restrict__ t1) {
  int half = blockIdx.z;
  const uint4* Apk = half ? Apk_t : Apk_h;
  const uint4* Wp = half ? Wp_t : Wp_h;
  const float* bias = half ? bt : bh;
  float* out = half ? t1 : h1;
  int mf0 = blockIdx.x * 4;
  int nt0 = blockIdx.y * 4;
  int tid = threadIdx.x;
  int wave = tid >> 6, lane = tid & 63;
  int wm = wave & 1, wn = wave >> 1;
  __shared__ __align__(16) uint4 Ash[2][512];
  __shared__ __align__(16) uint4 Bsh[2][512];

  f32x4 acc[2][2];
#pragma unroll
  for (int i = 0; i < 2; ++i)
#pragma unroll
    for (int j = 0; j < 2; ++j) acc[i][j] = (f32x4){0.f, 0.f, 0.f, 0.f};

  auto stage = [&](int s, int buf) {
#pragma unroll
    for (int i = 0; i < 2; ++i) {
      int c = wave * 2 + i;
      int cl = c >> 1, kslot = c & 1;
      gload_lds16(Apk + ((size_t)(mf0 + cl) * KS_MLP + s * 2 + kslot) * 64 + lane,
                  &Ash[buf][c * 64]);
      gload_lds16(Wp + ((size_t)(s * 2 + kslot) * 48 + nt0 + cl) * 64 + lane,
                  &Bsh[buf][c * 64]);
    }
  };

  stage(0, 0);
  __syncthreads();

  for (int s = 0; s < 25; ++s) {
    int cur = s & 1, nxt = cur ^ 1;
    if (s + 1 < 25) stage(s + 1, nxt);
    bf16x8 af[2][2], bf[2][2];
#pragma unroll
    for (int mf = 0; mf < 2; ++mf)
#pragma unroll
      for (int kc = 0; kc < 2; ++kc)
        af[mf][kc] = *(const bf16x8*)&Ash[cur][((wm * 2 + mf) * 2 + kc) * 64 + lane];
#pragma unroll
    for (int nf = 0; nf < 2; ++nf)
#pragma unroll
      for (int kc = 0; kc < 2; ++kc)
        bf[nf][kc] = *(const bf16x8*)&Bsh[cur][((wn * 2 + nf) * 2 + kc) * 64 + lane];
#pragma unroll
    for (int kc = 0; kc < 2; ++kc)
#pragma unroll
      for (int nf = 0; nf < 2; ++nf)
#pragma unroll
        for (int mf = 0; mf < 2; ++mf)
          acc[mf][nf] = __builtin_amdgcn_mfma_f32_16x16x32_bf16(af[mf][kc], bf[nf][kc], acc[mf][nf], 0, 0, 0);
    __syncthreads();
  }

#pragma unroll
  for (int mf = 0; mf < 2; ++mf)
#pragma unroll
    for (int nf = 0; nf < 2; ++nf) {
      int n = nt0 * 16 + (wn * 2 + nf) * 16 + (lane & 15);
      float bv = bias[n];
#pragma unroll
      for (int reg = 0; reg < 4; ++reg) {
        int l = (mf0 + wm * 2 + mf) * 16 + ((lane >> 4) << 2) + reg;
        if (l < L_)
          out[(size_t)l * H_ + n] = tanhf(acc[mf][nf][reg] + bv);
      }
    }
}

// ---------------------------------------------------------------------------
// K5a: pre-pack clsW -> fragment-major bf16 for the bilinear B-operand.
// ---------------------------------------------------------------------------
__global__ void pack_w(const float* __restrict__ clsW, uint4* __restrict__ Wfrag) {
  int nb = blockIdx.x;            // n*64 + b
  __shared__ float Wls[64][98];
  int tid = threadIdx.x;
  const float* src = clsW + (size_t)nb * 64 * R_;
  for (int idx = tid; idx < 64 * R_; idx += 256) {
    Wls[idx / R_][idx % R_] = src[idx];
  }
  __syncthreads();
  for (int u = tid; u < 896; u += 256) {
    int nf = u >> 7;
    int kc = (u >> 6) & 1;
    int lane = u & 63;
    int r = (lane & 15) + 16 * nf;
    unsigned w[4];
#pragma unroll
    for (int q = 0; q < 4; ++q) {
      int c0 = ((lane >> 4) << 3) + 2 * q + 32 * kc;
      float v0 = (r < R_) ? Wls[c0][r] : 0.f;
      float v1 = (r < R_) ? Wls[c0 + 1][r] : 0.f;
      w[q] = (unsigned)f2bf(v0) | ((unsigned)f2bf(v1) << 16);
    }
    uint4 o; o.x = w[0]; o.y = w[1]; o.z = w[2]; o.w = w[3];
    Wfrag[(size_t)nb * 896 + u] = o;
  }
}

// ---------------------------------------------------------------------------
// K5b v9: bilinear MFMA, BARRIER-FREE main loop. W-fragments read per-lane
// directly from L2 into VGPRs (no LDS for W, no __syncthreads in K-loop),
// register-double-buffered one step ahead. Waves fully independent:
// wm (m-half, mf=2) x kh (16 b's each); z-split across blocks; XCD decode
// keeps each (n,z) W-slice on one XCD L2. End: one barrier + kh-reduce.
// LDS: x1s 4224 + red 28672 = ~33 KB.
// ---------------------------------------------------------------------------
__global__ __launch_bounds__(256) void bilinear_mfma(
    const float* __restrict__ h1, const float* __restrict__ t1,
    const uint4* __restrict__ Wfrag, float* __restrict__ part,
    float* __restrict__ part2) {
  int blk = blockIdx.x;
  int xcd = blk & 7;
  int slot = blk >> 3;        // 0..107
  int pg = slot / 36;         // 0..2
  int j = slot % 36;          // l-tile index (64 rows)
  int p = pg * 8 + xcd;       // 0..23
  int n = p >> 1, z = p & 1;
  int l0 = j * 64;
  int tid = threadIdx.x;
  int wave = tid >> 6, lane = tid & 63;
  int wm = wave & 1, kh = wave >> 1;
  __shared__ unsigned short x1s[32][66];   // [b_local][row], padded
  __shared__ float red[128 * 56];          // kh-reduction buffer

  // x1 tile (32 b's for this z, 64 rows) -> LDS transposed, bf16
  for (int i = tid; i < 512; i += 256) {
    int row = i >> 3, cq = (i & 7) * 4;
    float4 v = make_float4(0, 0, 0, 0);
    if (l0 + row < L_)
      v = *(const float4*)(h1 + (size_t)(l0 + row) * H_ + n * 64 + z * 32 + cq);
    x1s[cq + 0][row] = f2bf(v.x);
    x1s[cq + 1][row] = f2bf(v.y);
    x1s[cq + 2][row] = f2bf(v.z);
    x1s[cq + 3][row] = f2bf(v.w);
  }

  // x2 fragments (b-invariant): 2 m-frags x 2 kc x 8 f32
  float x2f[2][2][8];
#pragma unroll
  for (int mf = 0; mf < 2; ++mf) {
    int row = l0 + wm * 32 + mf * 16 + (lane & 15);
#pragma unroll
    for (int kc = 0; kc < 2; ++kc) {
      float4 v0 = make_float4(0, 0, 0, 0), v1 = v0;
      if (row < L_) {
        const float* ptr = t1 + (size_t)row * H_ + n * 64 + kc * 32 + ((lane >> 4) << 3);
        v0 = *(const float4*)ptr;
        v1 = *(const float4*)(ptr + 4);
      }
      x2f[mf][kc][0] = v0.x; x2f[mf][kc][1] = v0.y;
      x2f[mf][kc][2] = v0.z; x2f[mf][kc][3] = v0.w;
      x2f[mf][kc][4] = v1.x; x2f[mf][kc][5] = v1.y;
      x2f[mf][kc][6] = v1.z; x2f[mf][kc][7] = v1.w;
    }
  }

  f32x4 acc[2][NF_];
#pragma unroll
  for (int mf = 0; mf < 2; ++mf)
#pragma unroll
    for (int nf = 0; nf < NF_; ++nf)
      acc[mf][nf] = (f32x4){0.f, 0.f, 0.f, 0.f};

  __syncthreads();   // x1s ready; no further barriers until reduction

  const uint4* gbase = Wfrag + (size_t)n * 64 * 896;
  int bbase = z * 32 + kh * 16;
  // W layout per (n,b): unit u = nf*128 + kc*64 + lane.
  uint4 wreg[7];
  {
    const uint4* gs = gbase + (size_t)bbase * 896 + lane;   // s=0: kc=0
#pragma unroll
    for (int nf = 0; nf < 7; ++nf) wreg[nf] = gs[nf * 128];
  }

#pragma unroll 2
  for (int s = 0; s < 32; ++s) {
    uint4 wnx[7];
    if (s + 1 < 32) {
      int b = bbase + ((s + 1) >> 1);
      int kcn = (s + 1) & 1;
      const uint4* gs = gbase + (size_t)b * 896 + kcn * 64 + lane;
#pragma unroll
      for (int nf = 0; nf < 7; ++nf) wnx[nf] = gs[nf * 128];
    }
    int bl = kh * 16 + (s >> 1);
    int kc = s & 1;
    bf16x8 afr[2];
#pragma unroll
    for (int mf = 0; mf < 2; ++mf) {
      float x1v = bf2f(x1s[bl][wm * 32 + mf * 16 + (lane & 15)]);
#pragma unroll
      for (int jj = 0; jj < 8; ++jj)
        afr[mf][jj] = (__bf16)(x1v * x2f[mf][kc][jj]);
    }
#pragma unroll
    for (int nf = 0; nf < NF_; ++nf) {
      union { uint4 u; bf16x8 b; } cvt;
      cvt.u = wreg[nf];
#pragma unroll
      for (int mf = 0; mf < 2; ++mf)
        acc[mf][nf] = __builtin_amdgcn_mfma_f32_16x16x32_bf16(
            afr[mf], cvt.b, acc[mf][nf], 0, 0, 0);
    }
#pragma unroll
    for (int nf = 0; nf < 7; ++nf) wreg[nf] = wnx[nf];
  }

  // kh-reduction via LDS (stride 56 floats = 2-way bank alias, free)
  int rbase = (wm * 64 + lane) * 56;
  if (kh == 1) {
#pragma unroll
    for (int mf = 0; mf < 2; ++mf)
#pragma unroll
      for (int nf = 0; nf < NF_; ++nf)
        *(f32x4*)&red[rbase + (mf * NF_ + nf) * 4] = acc[mf][nf];
  }
  __syncthreads();
  if (kh == 0) {
    float* dst = (z == 0) ? part : part2;
#pragma unroll
    for (int mf = 0; mf < 2; ++mf) {
#pragma unroll
      for (int nf = 0; nf < NF_; ++nf) {
        acc[mf][nf] += *(const f32x4*)&red[rbase + (mf * NF_ + nf) * 4];
        int r = nf * 16 + (lane & 15);
        if (r < R_) {
#pragma unroll
          for (int reg = 0; reg < 4; ++reg) {
            int l = l0 + wm * 32 + mf * 16 + ((lane >> 4) << 2) + reg;
            if (l < L_)
              dst[((size_t)n * L_ + l) * R_ + r] = acc[mf][nf][reg];
          }
        }
      }
    }
  }
}

// ---------------------------------------------------------------------------
// K6: reduce 24 partial slices (12 in part, 12 in part2), add clsb.
// ---------------------------------------------------------------------------
__global__ void reduce_logits(const float* __restrict__ part, const float* __restrict__ part2,
                              const float* __restrict__ clsb, float* __restrict__ out) {
  int idx = blockIdx.x * 256 + threadIdx.x;
  if (idx < L_ * R_) {
    int r = idx % R_;
    float s = clsb[r];
#pragma unroll
    for (int nn = 0; nn < NB_; ++nn)
      s += part[(size_t)nn * L_ * R_ + idx] + part2[(size_t)nn * L_ * R_ + idx];
    out[idx] = s;
  }
}

extern "C" void kernel_launch(void* const* d_in, const int* in_sizes, int n_in,
                              void* d_out, int out_size, void* d_ws, size_t ws_size,
                              hipStream_t stream) {
  const float* hs   = (const float*)d_in[0];
  const float* attn = (const float*)d_in[1];
  const float* mask = (const float*)d_in[2];
  const int*   head = (const int*)d_in[3];
  const int*   tail = (const int*)d_in[4];
  const int*   etyp = (const int*)d_in[5];
  const float* ttab = (const float*)d_in[6];
  const float* dtab = (const float*)d_in[7];
  const float* Wh   = (const float*)d_in[8];
  const float* bh   = (const float*)d_in[9];
  const float* Wt   = (const float*)d_in[10];
  const float* bt   = (const float*)d_in[11];
  const float* clsW = (const float*)d_in[12];
  const float* clsb = (const float*)d_in[13];
  float* out = (float*)d_out;

  float* ws = (float*)d_ws;
  float* ent_att  = ws; ws += (size_t)B_ * E_ * S_;
  float* ent_feat = ws; ws += (size_t)B_ * E_ * H_;
  float* ht_att   = ws; ws += (size_t)L_ * S_;
  float* ht_info  = ws; ws += (size_t)L_ * H_;
  float* h1       = ws; ws += (size_t)L_ * H_;
  float* t1       = ws; ws += (size_t)L_ * H_;
  float* part     = ws; ws += (size_t)NB_ * L_ * R_;
  uint4* Wpack_h  = (uint4*)ws; ws += (size_t)KS_MLP * 48 * 64 * 4;
  uint4* Wpack_t  = (uint4*)ws; ws += (size_t)KS_MLP * 48 * 64 * 4;
  uint4* hsPack   = (uint4*)ws; ws += (size_t)B_ * KS_HTI * 48 * 64 * 4;
  uint4* Wfrag    = (uint4*)ws; ws += (size_t)NB_ * 64 * 896 * 4;
  uint4* allx_h   = (uint4*)ws; ws += (size_t)MF_MLP * KS_MLP * 64 * 4;
  uint4* allx_t   = (uint4*)ws; ws += (size_t)MF_MLP * KS_MLP * 64 * 4;
  int* meta = (int*)ws;
  // part2 (12 slices, 10.3 MB) aliases allx_h+allx_t (13.7 MB), dead after mlp.
  float* part2 = (float*)allx_h;

  ent_prep<<<B_ * E_, 256, 0, stream>>>(attn, hs, head, tail, ent_att, ent_feat);
  pair_att<<<L_, 256, 0, stream>>>(ent_att, mask, head, tail, etyp, ht_att, meta);
  pack_hs<<<(B_ * KS_HTI * 48 * 64) / 256, 256, 0, stream>>>(hs, hsPack);
  htinfo_mfma<<<dim3(9, 12, B_), 256, 0, stream>>>(ht_att, hsPack, ht_info);
  pack_Wmlp<<<dim3((KS_MLP * 48 * 64) / 256, 2), 256, 0, stream>>>(Wh, Wt, Wpack_h, Wpack_t);
  pack_allx<<<(2 * MF_MLP * KS_MLP * 64) / 256, 256, 0, stream>>>(
      ent_feat, ht_info, ttab, dtab, meta, allx_h, allx_t);
  mlp_mfma<<<dim3(35, 12, 2), 256, 0, stream>>>(allx_h, allx_t,
      Wpack_h, Wpack_t, bh, bt, h1, t1);
  pack_w<<<NB_ * 64, 256, 0, stream>>>(clsW, Wfrag);
  bilinear_mfma<<<864, 256, 0, stream>>>(h1, t1, Wfrag, part, part2);
  reduce_logits<<<(L_ * R_ + 255) / 256, 256, 0, stream>>>(part, part2, clsb, out);
}